// Round 2
// baseline (1744.613 us; speedup 1.0000x reference)
//
#include <hip/hip_runtime.h>
#include <cstdint>

#define NN 100000
#define NE 1600000
#define DD 128

// ---------------- utility fills ----------------
__global__ __launch_bounds__(256) void fill_zero4(float4* __restrict__ p, int n4) {
    int i = blockIdx.x * 256 + threadIdx.x;
    if (i < n4) p[i] = make_float4(0.f, 0.f, 0.f, 0.f);
}

__global__ __launch_bounds__(256) void init_deg(float* __restrict__ deg) {
    int i = blockIdx.x * 256 + threadIdx.x;
    if (i < NN) deg[i] = 1.0f;   // self-loop weight 1
}

// deg[dst] += w  (1.6M atomics, cheap)
__global__ __launch_bounds__(256) void deg_acc(const int* __restrict__ dst,
                                               const float* __restrict__ w,
                                               float* __restrict__ deg) {
    int e = blockIdx.x * 256 + threadIdx.x;
    if (e < NE) atomicAdd(&deg[dst[e]], w[e]);
}

// norm[e] = rsqrt(deg[src]) * w * rsqrt(deg[dst])
__global__ __launch_bounds__(256) void norm_k(const int* __restrict__ src,
                                              const int* __restrict__ dst,
                                              const float* __restrict__ w,
                                              const float* __restrict__ deg,
                                              float* __restrict__ norm) {
    int e = blockIdx.x * 256 + threadIdx.x;
    if (e < NE) {
        float ds = rsqrtf(deg[src[e]]);
        float dd = rsqrtf(deg[dst[e]]);
        norm[e] = ds * w[e] * dd;
    }
}

// ---------------- GEMM: H[nrows x 128] = X[nrows x 128] @ W[128 x 128] ----------------
// fp32, no MFMA on CDNA4 -> vector ALU. W staged in LDS (64 KB), X via L1.
// Block: 256 threads, 64 rows/block. Thread = 4 rows x 8 cols register tile.
__global__ __launch_bounds__(256) void gemm_nn(const float* __restrict__ X,
                                               const float* __restrict__ W,
                                               float* __restrict__ H, int nrows) {
    __shared__ float Ws[DD * DD];          // 64 KB
    int tid = threadIdx.x;
    const float4* W4 = (const float4*)W;
    float4* Ws4 = (float4*)Ws;
#pragma unroll
    for (int i = 0; i < 16; ++i) Ws4[tid + 256 * i] = W4[tid + 256 * i];
    __syncthreads();

    int row0 = blockIdx.x * 64;
    int tx = tid & 15;        // col group: cols tx*8 .. tx*8+7
    int ty = tid >> 4;        // row group: rows ty*4 .. ty*4+3

    int rows[4];
#pragma unroll
    for (int r = 0; r < 4; ++r) {
        int g = row0 + ty * 4 + r;
        rows[r] = g < nrows ? g : (nrows - 1);   // clamp; masked at store
    }

    float acc[4][8];
#pragma unroll
    for (int r = 0; r < 4; ++r)
#pragma unroll
        for (int j = 0; j < 8; ++j) acc[r][j] = 0.f;

    for (int k = 0; k < DD; k += 4) {
        float4 xv[4];
#pragma unroll
        for (int r = 0; r < 4; ++r)
            xv[r] = *(const float4*)&X[(long)rows[r] * DD + k];
#pragma unroll
        for (int kk = 0; kk < 4; ++kk) {
            float4 w0 = *(const float4*)&Ws[(k + kk) * DD + tx * 8];
            float4 w1 = *(const float4*)&Ws[(k + kk) * DD + tx * 8 + 4];
#pragma unroll
            for (int r = 0; r < 4; ++r) {
                float xs = (&xv[r].x)[kk];
                acc[r][0] += xs * w0.x;
                acc[r][1] += xs * w0.y;
                acc[r][2] += xs * w0.z;
                acc[r][3] += xs * w0.w;
                acc[r][4] += xs * w1.x;
                acc[r][5] += xs * w1.y;
                acc[r][6] += xs * w1.z;
                acc[r][7] += xs * w1.w;
            }
        }
    }

#pragma unroll
    for (int r = 0; r < 4; ++r) {
        int g = row0 + ty * 4 + r;
        if (g < nrows) {
            float4* o = (float4*)&H[(long)g * DD + tx * 8];
            o[0] = make_float4(acc[r][0], acc[r][1], acc[r][2], acc[r][3]);
            o[1] = make_float4(acc[r][4], acc[r][5], acc[r][6], acc[r][7]);
        }
    }
}

// ---------------- scatter: out[dst[e]*128 + c] += h[src[e]*128 + c] * norm[e] ----------------
// thread t -> edge e = t>>7, channel c = t&127; wave-uniform edge metadata.
__global__ __launch_bounds__(256) void scatter(const float* __restrict__ h,
                                               const int* __restrict__ src,
                                               const int* __restrict__ dst,
                                               const float* __restrict__ norm,
                                               float* __restrict__ out) {
    int t = blockIdx.x * 256 + threadIdx.x;   // < NE*128 = 204.8M < 2^31
    int e = t >> 7;
    int c = t & 127;
    float v = h[(long)src[e] * DD + c] * norm[e];
    atomicAdd(&out[(long)dst[e] * DD + c], v);
}

// ---------------- finalize: += self-loop + bias, PReLU ----------------
__global__ __launch_bounds__(256) void finalize(const float* __restrict__ acc,
                                                const float* __restrict__ h,
                                                const float* __restrict__ deg,
                                                const float* __restrict__ b,
                                                const float* __restrict__ a,
                                                float* __restrict__ xout) {
    int i = blockIdx.x * 256 + threadIdx.x;   // < NN*DD
    int node = i >> 7;
    int c = i & 127;
    // self-loop: norm = rsqrt(deg)^2 = 1/deg (deg >= 1 always)
    float v = acc[i] + h[i] / deg[node] + b[c];
    xout[i] = v >= 0.f ? v : a[c] * v;
}

extern "C" void kernel_launch(void* const* d_in, const int* in_sizes, int n_in,
                              void* d_out, int out_size, void* d_ws, size_t ws_size,
                              hipStream_t stream) {
    const float* feat = (const float*)d_in[0];
    const int*   ei   = (const int*)d_in[1];     // [2, NE] int
    const float* ew   = (const float*)d_in[2];
    const float* W1   = (const float*)d_in[3];
    const float* b1   = (const float*)d_in[4];
    const float* a1   = (const float*)d_in[5];
    const float* W2   = (const float*)d_in[6];
    const float* b2   = (const float*)d_in[7];
    const float* a2   = (const float*)d_in[8];
    float* out = (float*)d_out;

    const int* srcp = ei;
    const int* dstp = ei + NE;

    // workspace layout (floats)
    float* ws   = (float*)d_ws;
    float* deg  = ws;                       // NN
    float* norm = ws + 100000;              // NE
    float* h    = ws + 100000 + NE;         // NN*DD   (16B aligned)
    float* accb = h + (size_t)NN * DD;      // NN*DD   (16B aligned)

    // ---- normalization precompute ----
    init_deg<<<(NN + 255) / 256, 256, 0, stream>>>(deg);
    deg_acc<<<NE / 256, 256, 0, stream>>>(dstp, ew, deg);
    norm_k<<<NE / 256, 256, 0, stream>>>(srcp, dstp, ew, deg, norm);

    const int gemm_blocks = (NN + 63) / 64;
    const int n4 = NN * DD / 4;
    const int scat_blocks = NE * DD / 256;   // 800000 (beware int div order!)

    // ---- layer 1 ----
    gemm_nn<<<gemm_blocks, 256, 0, stream>>>(feat, W1, h, NN);
    fill_zero4<<<n4 / 256, 256, 0, stream>>>((float4*)accb, n4);
    scatter<<<scat_blocks, 256, 0, stream>>>(h, srcp, dstp, norm, accb);
    finalize<<<NN * DD / 256, 256, 0, stream>>>(accb, h, deg, b1, a1, accb);     // in-place -> x1

    // ---- layer 2 ----
    gemm_nn<<<gemm_blocks, 256, 0, stream>>>(accb, W2, h, NN);
    fill_zero4<<<n4 / 256, 256, 0, stream>>>((float4*)out, n4);
    scatter<<<scat_blocks, 256, 0, stream>>>(h, srcp, dstp, norm, out);
    finalize<<<NN * DD / 256, 256, 0, stream>>>(out, h, deg, b2, a2, out);
}

// Round 3
// 900.994 us; speedup vs baseline: 1.9363x; 1.9363x over previous
//
#include <hip/hip_runtime.h>
#include <cstdint>

#define NN 100000
#define NE 1600000
#define DD 128

// ---------------- CSR build ----------------
__global__ __launch_bounds__(256) void init_k(float* __restrict__ deg,
                                              int* __restrict__ hist,
                                              int* __restrict__ gcur) {
    int i = blockIdx.x * 256 + threadIdx.x;
    if (i < NN) { deg[i] = 1.0f; hist[i] = 0; }
    if (i == 0) gcur[0] = 0;
}

// deg[dst] += w ; hist[dst] += 1
__global__ __launch_bounds__(256) void hist_k(const int* __restrict__ dst,
                                              const float* __restrict__ w,
                                              float* __restrict__ deg,
                                              int* __restrict__ hist) {
    int e = blockIdx.x * 256 + threadIdx.x;
    if (e < NE) {
        int d = dst[e];
        atomicAdd(&deg[d], w[e]);
        atomicAdd(&hist[d], 1);
    }
}

// rowstart[i] = cursor[i] = wave-aggregated bump-allocation of hist[i] slots.
// Row placement order is irrelevant (only per-node contiguity matters).
__global__ __launch_bounds__(256) void assign_rows(const int* __restrict__ hist,
                                                   int* __restrict__ rowstart,
                                                   int* __restrict__ cursor,
                                                   int* __restrict__ gcur) {
    int i = blockIdx.x * 256 + threadIdx.x;
    if (i < NN) {
        int s = atomicAdd(gcur, hist[i]);   // LLVM wave-aggregates this
        rowstart[i] = s;
        cursor[i] = s;
    }
}

// place edge e into its dst row; compute norm on the fly
__global__ __launch_bounds__(256) void csr_scatter(const int* __restrict__ src,
                                                   const int* __restrict__ dst,
                                                   const float* __restrict__ w,
                                                   const float* __restrict__ deg,
                                                   int* __restrict__ cursor,
                                                   int* __restrict__ src_sorted,
                                                   float* __restrict__ norm_sorted) {
    int e = blockIdx.x * 256 + threadIdx.x;
    if (e < NE) {
        int d = dst[e];
        int s = src[e];
        int p = atomicAdd(&cursor[d], 1);
        src_sorted[p] = s;
        norm_sorted[p] = rsqrtf(deg[s]) * w[e] * rsqrtf(deg[d]);
    }
}

// ---------------- GEMM: H[nrows x 128] = X[nrows x 128] @ W[128 x 128] ----------------
__global__ __launch_bounds__(256) void gemm_nn(const float* __restrict__ X,
                                               const float* __restrict__ W,
                                               float* __restrict__ H, int nrows) {
    __shared__ float Ws[DD * DD];          // 64 KB
    int tid = threadIdx.x;
    const float4* W4 = (const float4*)W;
    float4* Ws4 = (float4*)Ws;
#pragma unroll
    for (int i = 0; i < 16; ++i) Ws4[tid + 256 * i] = W4[tid + 256 * i];
    __syncthreads();

    int row0 = blockIdx.x * 64;
    int tx = tid & 15;
    int ty = tid >> 4;

    int rows[4];
#pragma unroll
    for (int r = 0; r < 4; ++r) {
        int g = row0 + ty * 4 + r;
        rows[r] = g < nrows ? g : (nrows - 1);
    }

    float acc[4][8];
#pragma unroll
    for (int r = 0; r < 4; ++r)
#pragma unroll
        for (int j = 0; j < 8; ++j) acc[r][j] = 0.f;

    for (int k = 0; k < DD; k += 4) {
        float4 xv[4];
#pragma unroll
        for (int r = 0; r < 4; ++r)
            xv[r] = *(const float4*)&X[(long)rows[r] * DD + k];
#pragma unroll
        for (int kk = 0; kk < 4; ++kk) {
            float4 w0 = *(const float4*)&Ws[(k + kk) * DD + tx * 8];
            float4 w1 = *(const float4*)&Ws[(k + kk) * DD + tx * 8 + 4];
#pragma unroll
            for (int r = 0; r < 4; ++r) {
                float xs = (&xv[r].x)[kk];
                acc[r][0] += xs * w0.x;
                acc[r][1] += xs * w0.y;
                acc[r][2] += xs * w0.z;
                acc[r][3] += xs * w0.w;
                acc[r][4] += xs * w1.x;
                acc[r][5] += xs * w1.y;
                acc[r][6] += xs * w1.z;
                acc[r][7] += xs * w1.w;
            }
        }
    }

#pragma unroll
    for (int r = 0; r < 4; ++r) {
        int g = row0 + ty * 4 + r;
        if (g < nrows) {
            float4* o = (float4*)&H[(long)g * DD + tx * 8];
            o[0] = make_float4(acc[r][0], acc[r][1], acc[r][2], acc[r][3]);
            o[1] = make_float4(acc[r][4], acc[r][5], acc[r][6], acc[r][7]);
        }
    }
}

// ---------------- fused gather + self-loop + bias + PReLU ----------------
// 256 threads = 2 nodes x 128 channels. Registers accumulate; one write per elem.
__global__ __launch_bounds__(256) void gather_finalize(const float* __restrict__ h,
                                                       const int* __restrict__ src_sorted,
                                                       const float* __restrict__ norm_sorted,
                                                       const int* __restrict__ rowstart,
                                                       const int* __restrict__ hist,
                                                       const float* __restrict__ deg,
                                                       const float* __restrict__ b,
                                                       const float* __restrict__ a,
                                                       float* __restrict__ xout) {
    int tid = threadIdx.x;
    int node = blockIdx.x * 2 + (tid >> 7);   // NN even, grid = NN/2
    int c = tid & 127;

    int start = rowstart[node];
    int cnt = hist[node];
    // self-loop: norm = 1/deg
    float acc = h[(long)node * DD + c] / deg[node];

    int j = 0;
    for (; j + 1 < cnt; j += 2) {
        int s0 = src_sorted[start + j];
        int s1 = src_sorted[start + j + 1];
        float n0 = norm_sorted[start + j];
        float n1 = norm_sorted[start + j + 1];
        float v0 = h[(long)s0 * DD + c];
        float v1 = h[(long)s1 * DD + c];
        acc += v0 * n0;
        acc += v1 * n1;
    }
    if (j < cnt) {
        int s0 = src_sorted[start + j];
        acc += h[(long)s0 * DD + c] * norm_sorted[start + j];
    }

    float v = acc + b[c];
    xout[(long)node * DD + c] = v >= 0.f ? v : a[c] * v;
}

extern "C" void kernel_launch(void* const* d_in, const int* in_sizes, int n_in,
                              void* d_out, int out_size, void* d_ws, size_t ws_size,
                              hipStream_t stream) {
    const float* feat = (const float*)d_in[0];
    const int*   ei   = (const int*)d_in[1];     // [2, NE]
    const float* ew   = (const float*)d_in[2];
    const float* W1   = (const float*)d_in[3];
    const float* b1   = (const float*)d_in[4];
    const float* a1   = (const float*)d_in[5];
    const float* W2   = (const float*)d_in[6];
    const float* b2   = (const float*)d_in[7];
    const float* a2   = (const float*)d_in[8];
    float* out = (float*)d_out;

    const int* srcp = ei;
    const int* dstp = ei + NE;

    // workspace layout (4-byte units) — ~65.6 MB total
    char* wsb = (char*)d_ws;
    float* deg        = (float*)wsb;                           // NN
    int*   hist       = (int*)(wsb + 4ull * NN);               // NN
    int*   rowstart   = (int*)(wsb + 8ull * NN);               // NN
    int*   cursor     = (int*)(wsb + 12ull * NN);              // NN
    int*   gcur       = (int*)(wsb + 16ull * NN);              // 4 ints (pad)
    int*   src_sorted = (int*)(wsb + 16ull * NN + 16);         // NE
    float* norm_sorted= (float*)(wsb + 16ull * NN + 16 + 4ull * NE); // NE
    float* h          = (float*)(wsb + 16ull * NN + 16 + 8ull * NE); // NN*DD
    float* x1         = out;   // layer-1 output lives in d_out (overwritten by layer 2)

    // ---- CSR build + normalization ----
    init_k<<<(NN + 255) / 256, 256, 0, stream>>>(deg, hist, gcur);
    hist_k<<<NE / 256, 256, 0, stream>>>(dstp, ew, deg, hist);
    assign_rows<<<(NN + 255) / 256, 256, 0, stream>>>(hist, rowstart, cursor, gcur);
    csr_scatter<<<NE / 256, 256, 0, stream>>>(srcp, dstp, ew, deg, cursor,
                                              src_sorted, norm_sorted);

    const int gemm_blocks = (NN + 63) / 64;
    const int gath_blocks = NN / 2;

    // ---- layer 1 ----
    gemm_nn<<<gemm_blocks, 256, 0, stream>>>(feat, W1, h, NN);
    gather_finalize<<<gath_blocks, 256, 0, stream>>>(h, src_sorted, norm_sorted,
                                                     rowstart, hist, deg, b1, a1, x1);
    // ---- layer 2 ----
    gemm_nn<<<gemm_blocks, 256, 0, stream>>>(x1, W2, h, NN);
    gather_finalize<<<gath_blocks, 256, 0, stream>>>(h, src_sorted, norm_sorted,
                                                     rowstart, hist, deg, b2, a2, out);
}

// Round 4
// 637.213 us; speedup vs baseline: 2.7379x; 1.4140x over previous
//
#include <hip/hip_runtime.h>
#include <cstdint>

#define NN 100000
#define NE 1600000
#define DD 128

typedef unsigned int uint;
typedef unsigned short ushort;

// fp32 -> bf16 bits, round-to-nearest-even
__device__ inline uint f2bf(float f) {
    uint u = __float_as_uint(f);
    return (u + 0x7fffu + ((u >> 16) & 1u)) >> 16;
}

// ---------------- CSR build ----------------
__global__ __launch_bounds__(256) void init_k(float* __restrict__ deg,
                                              int* __restrict__ hist,
                                              int* __restrict__ gcur) {
    int i = blockIdx.x * 256 + threadIdx.x;
    if (i < NN) { deg[i] = 1.0f; hist[i] = 0; }
    if (i == 0) gcur[0] = 0;
}

__global__ __launch_bounds__(256) void hist_k(const int* __restrict__ dst,
                                              const float* __restrict__ w,
                                              float* __restrict__ deg,
                                              int* __restrict__ hist) {
    int e = blockIdx.x * 256 + threadIdx.x;
    if (e < NE) {
        int d = dst[e];
        atomicAdd(&deg[d], w[e]);
        atomicAdd(&hist[d], 1);
    }
}

__global__ __launch_bounds__(256) void assign_rows(const int* __restrict__ hist,
                                                   int* __restrict__ rowstart,
                                                   int* __restrict__ cursor,
                                                   int* __restrict__ gcur) {
    int i = blockIdx.x * 256 + threadIdx.x;
    if (i < NN) {
        int s = atomicAdd(gcur, hist[i]);   // wave-aggregated bump alloc
        rowstart[i] = s;
        cursor[i] = s;
    }
}

// place edge into its dst row as packed {src, norm_bits}
__global__ __launch_bounds__(256) void csr_scatter(const int* __restrict__ src,
                                                   const int* __restrict__ dst,
                                                   const float* __restrict__ w,
                                                   const float* __restrict__ deg,
                                                   int* __restrict__ cursor,
                                                   int2* __restrict__ edges) {
    int e = blockIdx.x * 256 + threadIdx.x;
    if (e < NE) {
        int d = dst[e];
        int s = src[e];
        int p = atomicAdd(&cursor[d], 1);
        float nrm = rsqrtf(deg[s]) * w[e] * rsqrtf(deg[d]);
        edges[p] = make_int2(s, __float_as_int(nrm));
    }
}

// ---------------- GEMM: HB[nrows x 128](bf16) = X[nrows x 128] @ W[128 x 128] ----------------
__global__ __launch_bounds__(256) void gemm_nn(const float* __restrict__ X,
                                               const float* __restrict__ W,
                                               ushort* __restrict__ HB, int nrows) {
    __shared__ float Ws[DD * DD];          // 64 KB
    int tid = threadIdx.x;
    const float4* W4 = (const float4*)W;
    float4* Ws4 = (float4*)Ws;
#pragma unroll
    for (int i = 0; i < 16; ++i) Ws4[tid + 256 * i] = W4[tid + 256 * i];
    __syncthreads();

    int row0 = blockIdx.x * 64;
    int tx = tid & 15;
    int ty = tid >> 4;

    int rows[4];
#pragma unroll
    for (int r = 0; r < 4; ++r) {
        int g = row0 + ty * 4 + r;
        rows[r] = g < nrows ? g : (nrows - 1);
    }

    float acc[4][8];
#pragma unroll
    for (int r = 0; r < 4; ++r)
#pragma unroll
        for (int j = 0; j < 8; ++j) acc[r][j] = 0.f;

    for (int k = 0; k < DD; k += 4) {
        float4 xv[4];
#pragma unroll
        for (int r = 0; r < 4; ++r)
            xv[r] = *(const float4*)&X[(long)rows[r] * DD + k];
#pragma unroll
        for (int kk = 0; kk < 4; ++kk) {
            float4 w0 = *(const float4*)&Ws[(k + kk) * DD + tx * 8];
            float4 w1 = *(const float4*)&Ws[(k + kk) * DD + tx * 8 + 4];
#pragma unroll
            for (int r = 0; r < 4; ++r) {
                float xs = (&xv[r].x)[kk];
                acc[r][0] += xs * w0.x;
                acc[r][1] += xs * w0.y;
                acc[r][2] += xs * w0.z;
                acc[r][3] += xs * w0.w;
                acc[r][4] += xs * w1.x;
                acc[r][5] += xs * w1.y;
                acc[r][6] += xs * w1.z;
                acc[r][7] += xs * w1.w;
            }
        }
    }

#pragma unroll
    for (int r = 0; r < 4; ++r) {
        int g = row0 + ty * 4 + r;
        if (g < nrows) {
            uint4 o;
            o.x = f2bf(acc[r][0]) | (f2bf(acc[r][1]) << 16);
            o.y = f2bf(acc[r][2]) | (f2bf(acc[r][3]) << 16);
            o.z = f2bf(acc[r][4]) | (f2bf(acc[r][5]) << 16);
            o.w = f2bf(acc[r][6]) | (f2bf(acc[r][7]) << 16);
            *(uint4*)&HB[(size_t)g * DD + tx * 8] = o;
        }
    }
}

// decode 4 bf16 (uint2) -> float4
__device__ inline float4 bf4(uint2 u) {
    float4 f;
    f.x = __uint_as_float(u.x << 16);
    f.y = __uint_as_float(u.x & 0xffff0000u);
    f.z = __uint_as_float(u.y << 16);
    f.w = __uint_as_float(u.y & 0xffff0000u);
    return f;
}

// ---------------- fused gather + self-loop + bias + PReLU ----------------
// lane = 4 channels; 32 lanes/node; 8 nodes per 256-block.
__global__ __launch_bounds__(256) void gather_finalize(const ushort* __restrict__ hb,
                                                       const int2* __restrict__ edges,
                                                       const int* __restrict__ rowstart,
                                                       const int* __restrict__ hist,
                                                       const float* __restrict__ deg,
                                                       const float* __restrict__ b,
                                                       const float* __restrict__ a,
                                                       float* __restrict__ xout) {
    int tid = threadIdx.x;
    int lane = tid & 31;                      // channels lane*4 .. lane*4+3
    int node = blockIdx.x * 8 + (tid >> 5);   // NN % 8 == 0

    int start = rowstart[node];
    int cnt = hist[node];
    float invd = 1.0f / deg[node];

    const uint2* hrow = (const uint2*)(hb + (size_t)node * DD) + lane;
    float4 self = bf4(*hrow);
    float4 acc0, acc1;
    acc0.x = self.x * invd; acc0.y = self.y * invd;
    acc0.z = self.z * invd; acc0.w = self.w * invd;
    acc1 = make_float4(0.f, 0.f, 0.f, 0.f);

    int j = 0;
    for (; j + 4 <= cnt; j += 4) {
        int2 e0 = edges[start + j];
        int2 e1 = edges[start + j + 1];
        int2 e2 = edges[start + j + 2];
        int2 e3 = edges[start + j + 3];
        uint2 u0 = *((const uint2*)(hb + (size_t)e0.x * DD) + lane);
        uint2 u1 = *((const uint2*)(hb + (size_t)e1.x * DD) + lane);
        uint2 u2 = *((const uint2*)(hb + (size_t)e2.x * DD) + lane);
        uint2 u3 = *((const uint2*)(hb + (size_t)e3.x * DD) + lane);
        float n0 = __int_as_float(e0.y), n1 = __int_as_float(e1.y);
        float n2 = __int_as_float(e2.y), n3 = __int_as_float(e3.y);
        float4 v0 = bf4(u0), v1 = bf4(u1), v2 = bf4(u2), v3 = bf4(u3);
        acc0.x += v0.x * n0; acc0.y += v0.y * n0; acc0.z += v0.z * n0; acc0.w += v0.w * n0;
        acc1.x += v1.x * n1; acc1.y += v1.y * n1; acc1.z += v1.z * n1; acc1.w += v1.w * n1;
        acc0.x += v2.x * n2; acc0.y += v2.y * n2; acc0.z += v2.z * n2; acc0.w += v2.w * n2;
        acc1.x += v3.x * n3; acc1.y += v3.y * n3; acc1.z += v3.z * n3; acc1.w += v3.w * n3;
    }
    for (; j < cnt; ++j) {
        int2 e = edges[start + j];
        uint2 u = *((const uint2*)(hb + (size_t)e.x * DD) + lane);
        float n = __int_as_float(e.y);
        float4 v = bf4(u);
        acc0.x += v.x * n; acc0.y += v.y * n; acc0.z += v.z * n; acc0.w += v.w * n;
    }

    float4 bb = ((const float4*)b)[lane];
    float4 aa = ((const float4*)a)[lane];
    float4 r;
    r.x = acc0.x + acc1.x + bb.x;
    r.y = acc0.y + acc1.y + bb.y;
    r.z = acc0.z + acc1.z + bb.z;
    r.w = acc0.w + acc1.w + bb.w;
    r.x = r.x >= 0.f ? r.x : aa.x * r.x;
    r.y = r.y >= 0.f ? r.y : aa.y * r.y;
    r.z = r.z >= 0.f ? r.z : aa.z * r.z;
    r.w = r.w >= 0.f ? r.w : aa.w * r.w;
    ((float4*)xout)[(size_t)node * 32 + lane] = r;
}

extern "C" void kernel_launch(void* const* d_in, const int* in_sizes, int n_in,
                              void* d_out, int out_size, void* d_ws, size_t ws_size,
                              hipStream_t stream) {
    const float* feat = (const float*)d_in[0];
    const int*   ei   = (const int*)d_in[1];     // [2, NE]
    const float* ew   = (const float*)d_in[2];
    const float* W1   = (const float*)d_in[3];
    const float* b1   = (const float*)d_in[4];
    const float* a1   = (const float*)d_in[5];
    const float* W2   = (const float*)d_in[6];
    const float* b2   = (const float*)d_in[7];
    const float* a2   = (const float*)d_in[8];
    float* out = (float*)d_out;

    const int* srcp = ei;
    const int* dstp = ei + NE;

    // workspace layout — ~40 MB
    char* wsb = (char*)d_ws;
    float* deg      = (float*)wsb;                            // NN
    int*   hist     = (int*)(wsb + 4ull * NN);                // NN
    int*   rowstart = (int*)(wsb + 8ull * NN);                // NN
    int*   cursor   = (int*)(wsb + 12ull * NN);               // NN
    int*   gcur     = (int*)(wsb + 16ull * NN);               // pad 16 B
    int2*  edges    = (int2*)(wsb + 16ull * NN + 16);         // NE int2
    ushort* hb      = (ushort*)(wsb + 16ull * NN + 16 + 8ull * NE); // NN*DD bf16
    float* x1       = out;   // layer-1 output in d_out (overwritten by layer 2)

    init_k<<<(NN + 255) / 256, 256, 0, stream>>>(deg, hist, gcur);
    hist_k<<<NE / 256, 256, 0, stream>>>(dstp, ew, deg, hist);
    assign_rows<<<(NN + 255) / 256, 256, 0, stream>>>(hist, rowstart, cursor, gcur);
    csr_scatter<<<NE / 256, 256, 0, stream>>>(srcp, dstp, ew, deg, cursor, edges);

    const int gemm_blocks = (NN + 63) / 64;
    const int gath_blocks = NN / 8;

    // ---- layer 1 ----
    gemm_nn<<<gemm_blocks, 256, 0, stream>>>(feat, W1, hb, NN);
    gather_finalize<<<gath_blocks, 256, 0, stream>>>(hb, edges, rowstart, hist, deg, b1, a1, x1);
    // ---- layer 2 ----
    gemm_nn<<<gemm_blocks, 256, 0, stream>>>(x1, W2, hb, NN);
    gather_finalize<<<gath_blocks, 256, 0, stream>>>(hb, edges, rowstart, hist, deg, b2, a2, out);
}

// Round 5
// 562.556 us; speedup vs baseline: 3.1012x; 1.1327x over previous
//
#include <hip/hip_runtime.h>
#include <cstdint>

#define NN 100000
#define NE 1600000
#define DD 128

typedef unsigned int uint;
typedef unsigned short ushort;
typedef unsigned long long u64;

#define WSCALE 4194304.0f        // 2^22 fixed-point for edge weights
#define WINV   (1.0f / 4194304.0f)

// fp32 -> bf16 bits, round-to-nearest-even
__device__ inline uint f2bf(float f) {
    uint u = __float_as_uint(f);
    return (u + 0x7fffu + ((u >> 16) & 1u)) >> 16;
}

// ---------------- CSR build ----------------
// zero the 8 sub-histograms + global cursor
__global__ __launch_bounds__(256) void zero_k(u64* __restrict__ hist8,
                                              int* __restrict__ gcur) {
    int i = blockIdx.x * 256 + threadIdx.x;   // grid covers 8*NN
    if (i < 8 * NN) hist8[i] = 0ull;
    if (i == 0) gcur[0] = 0;
}

// one u64 atomic per edge: count in high 32, fixed-point weight in low 32.
// sub-histogram selected by blockIdx&7 -> contention /8.
__global__ __launch_bounds__(256) void hist_k(const int* __restrict__ dst,
                                              const float* __restrict__ w,
                                              u64* __restrict__ hist8) {
    int e = blockIdx.x * 256 + threadIdx.x;
    if (e < NE) {
        int d = dst[e];
        uint q = (uint)(w[e] * WSCALE + 0.5f);
        u64 packed = ((u64)1 << 32) | (u64)q;
        atomicAdd(&hist8[(size_t)(blockIdx.x & 7) * NN + d], packed);
    }
}

// fold 8 copies -> deg/hist/rowstart + 8 per-node sub-cursors (prefix over copies)
__global__ __launch_bounds__(256) void reduce_assign(const u64* __restrict__ hist8,
                                                     float* __restrict__ deg,
                                                     int* __restrict__ hist,
                                                     int* __restrict__ rowstart,
                                                     int* __restrict__ cursor8,
                                                     int* __restrict__ gcur) {
    int i = blockIdx.x * 256 + threadIdx.x;
    if (i >= NN) return;
    int cnt[8];
    u64 fixsum = 0;
    int tot = 0;
#pragma unroll
    for (int c = 0; c < 8; ++c) {
        u64 v = hist8[(size_t)c * NN + i];
        cnt[c] = (int)(v >> 32);
        fixsum += (v & 0xffffffffull);
        tot += cnt[c];
    }
    deg[i] = 1.0f + (float)fixsum * WINV;
    hist[i] = tot;
    int s = atomicAdd(gcur, tot);             // wave-aggregated bump alloc
    rowstart[i] = s;
    int run = s;
#pragma unroll
    for (int c = 0; c < 8; ++c) {
        cursor8[(size_t)c * NN + i] = run;
        run += cnt[c];
    }
}

// place edge into its dst row as packed {src, norm_bits}; per-copy cursor (blockIdx&7)
__global__ __launch_bounds__(256) void csr_scatter(const int* __restrict__ src,
                                                   const int* __restrict__ dst,
                                                   const float* __restrict__ w,
                                                   const float* __restrict__ deg,
                                                   int* __restrict__ cursor8,
                                                   int2* __restrict__ edges) {
    int e = blockIdx.x * 256 + threadIdx.x;
    if (e < NE) {
        int d = dst[e];
        int s = src[e];
        int p = atomicAdd(&cursor8[(size_t)(blockIdx.x & 7) * NN + d], 1);
        float nrm = rsqrtf(deg[s]) * w[e] * rsqrtf(deg[d]);
        edges[p] = make_int2(s, __float_as_int(nrm));
    }
}

// ---------------- GEMM: HB[nrows x 128](bf16) = X[nrows x 128] @ W[128 x 128] ----------------
__global__ __launch_bounds__(256) void gemm_nn(const float* __restrict__ X,
                                               const float* __restrict__ W,
                                               ushort* __restrict__ HB, int nrows) {
    __shared__ float Ws[DD * DD];          // 64 KB
    int tid = threadIdx.x;
    const float4* W4 = (const float4*)W;
    float4* Ws4 = (float4*)Ws;
#pragma unroll
    for (int i = 0; i < 16; ++i) Ws4[tid + 256 * i] = W4[tid + 256 * i];
    __syncthreads();

    int row0 = blockIdx.x * 64;
    int tx = tid & 15;
    int ty = tid >> 4;

    int rows[4];
#pragma unroll
    for (int r = 0; r < 4; ++r) {
        int g = row0 + ty * 4 + r;
        rows[r] = g < nrows ? g : (nrows - 1);
    }

    float acc[4][8];
#pragma unroll
    for (int r = 0; r < 4; ++r)
#pragma unroll
        for (int j = 0; j < 8; ++j) acc[r][j] = 0.f;

    for (int k = 0; k < DD; k += 4) {
        float4 xv[4];
#pragma unroll
        for (int r = 0; r < 4; ++r)
            xv[r] = *(const float4*)&X[(long)rows[r] * DD + k];
#pragma unroll
        for (int kk = 0; kk < 4; ++kk) {
            float4 w0 = *(const float4*)&Ws[(k + kk) * DD + tx * 8];
            float4 w1 = *(const float4*)&Ws[(k + kk) * DD + tx * 8 + 4];
#pragma unroll
            for (int r = 0; r < 4; ++r) {
                float xs = (&xv[r].x)[kk];
                acc[r][0] += xs * w0.x;
                acc[r][1] += xs * w0.y;
                acc[r][2] += xs * w0.z;
                acc[r][3] += xs * w0.w;
                acc[r][4] += xs * w1.x;
                acc[r][5] += xs * w1.y;
                acc[r][6] += xs * w1.z;
                acc[r][7] += xs * w1.w;
            }
        }
    }

#pragma unroll
    for (int r = 0; r < 4; ++r) {
        int g = row0 + ty * 4 + r;
        if (g < nrows) {
            uint4 o;
            o.x = f2bf(acc[r][0]) | (f2bf(acc[r][1]) << 16);
            o.y = f2bf(acc[r][2]) | (f2bf(acc[r][3]) << 16);
            o.z = f2bf(acc[r][4]) | (f2bf(acc[r][5]) << 16);
            o.w = f2bf(acc[r][6]) | (f2bf(acc[r][7]) << 16);
            *(uint4*)&HB[(size_t)g * DD + tx * 8] = o;
        }
    }
}

// decode 4 bf16 (uint2) -> float4
__device__ inline float4 bf4(uint2 u) {
    float4 f;
    f.x = __uint_as_float(u.x << 16);
    f.y = __uint_as_float(u.x & 0xffff0000u);
    f.z = __uint_as_float(u.y << 16);
    f.w = __uint_as_float(u.y & 0xffff0000u);
    return f;
}

// ---------------- fused gather + self-loop + bias + PReLU ----------------
// lane = 4 channels; 32 lanes/node; 8 nodes per 256-block.
__global__ __launch_bounds__(256) void gather_finalize(const ushort* __restrict__ hb,
                                                       const int2* __restrict__ edges,
                                                       const int* __restrict__ rowstart,
                                                       const int* __restrict__ hist,
                                                       const float* __restrict__ deg,
                                                       const float* __restrict__ b,
                                                       const float* __restrict__ a,
                                                       float* __restrict__ xout) {
    int tid = threadIdx.x;
    int lane = tid & 31;                      // channels lane*4 .. lane*4+3
    int node = blockIdx.x * 8 + (tid >> 5);   // NN % 8 == 0

    int start = rowstart[node];
    int cnt = hist[node];
    float invd = 1.0f / deg[node];

    const uint2* hrow = (const uint2*)(hb + (size_t)node * DD) + lane;
    float4 self = bf4(*hrow);
    float4 acc0, acc1;
    acc0.x = self.x * invd; acc0.y = self.y * invd;
    acc0.z = self.z * invd; acc0.w = self.w * invd;
    acc1 = make_float4(0.f, 0.f, 0.f, 0.f);

    int j = 0;
    for (; j + 4 <= cnt; j += 4) {
        int2 e0 = edges[start + j];
        int2 e1 = edges[start + j + 1];
        int2 e2 = edges[start + j + 2];
        int2 e3 = edges[start + j + 3];
        uint2 u0 = *((const uint2*)(hb + (size_t)e0.x * DD) + lane);
        uint2 u1 = *((const uint2*)(hb + (size_t)e1.x * DD) + lane);
        uint2 u2 = *((const uint2*)(hb + (size_t)e2.x * DD) + lane);
        uint2 u3 = *((const uint2*)(hb + (size_t)e3.x * DD) + lane);
        float n0 = __int_as_float(e0.y), n1 = __int_as_float(e1.y);
        float n2 = __int_as_float(e2.y), n3 = __int_as_float(e3.y);
        float4 v0 = bf4(u0), v1 = bf4(u1), v2 = bf4(u2), v3 = bf4(u3);
        acc0.x += v0.x * n0; acc0.y += v0.y * n0; acc0.z += v0.z * n0; acc0.w += v0.w * n0;
        acc1.x += v1.x * n1; acc1.y += v1.y * n1; acc1.z += v1.z * n1; acc1.w += v1.w * n1;
        acc0.x += v2.x * n2; acc0.y += v2.y * n2; acc0.z += v2.z * n2; acc0.w += v2.w * n2;
        acc1.x += v3.x * n3; acc1.y += v3.y * n3; acc1.z += v3.z * n3; acc1.w += v3.w * n3;
    }
    for (; j < cnt; ++j) {
        int2 e = edges[start + j];
        uint2 u = *((const uint2*)(hb + (size_t)e.x * DD) + lane);
        float n = __int_as_float(e.y);
        float4 v = bf4(u);
        acc0.x += v.x * n; acc0.y += v.y * n; acc0.z += v.z * n; acc0.w += v.w * n;
    }

    float4 bb = ((const float4*)b)[lane];
    float4 aa = ((const float4*)a)[lane];
    float4 r;
    r.x = acc0.x + acc1.x + bb.x;
    r.y = acc0.y + acc1.y + bb.y;
    r.z = acc0.z + acc1.z + bb.z;
    r.w = acc0.w + acc1.w + bb.w;
    r.x = r.x >= 0.f ? r.x : aa.x * r.x;
    r.y = r.y >= 0.f ? r.y : aa.y * r.y;
    r.z = r.z >= 0.f ? r.z : aa.z * r.z;
    r.w = r.w >= 0.f ? r.w : aa.w * r.w;
    ((float4*)xout)[(size_t)node * 32 + lane] = r;
}

extern "C" void kernel_launch(void* const* d_in, const int* in_sizes, int n_in,
                              void* d_out, int out_size, void* d_ws, size_t ws_size,
                              hipStream_t stream) {
    const float* feat = (const float*)d_in[0];
    const int*   ei   = (const int*)d_in[1];     // [2, NE]
    const float* ew   = (const float*)d_in[2];
    const float* W1   = (const float*)d_in[3];
    const float* b1   = (const float*)d_in[4];
    const float* a1   = (const float*)d_in[5];
    const float* W2   = (const float*)d_in[6];
    const float* b2   = (const float*)d_in[7];
    const float* a2   = (const float*)d_in[8];
    float* out = (float*)d_out;

    const int* srcp = ei;
    const int* dstp = ei + NE;

    // workspace layout — ~49 MB
    char* wsb = (char*)d_ws;
    u64*   hist8    = (u64*)wsb;                               // 8*NN u64  (6.4 MB)
    int*   cursor8  = (int*)(wsb + 64ull * NN);                // 8*NN int  (3.2 MB)
    float* deg      = (float*)(wsb + 96ull * NN);              // NN
    int*   hist     = (int*)(wsb + 100ull * NN);               // NN
    int*   rowstart = (int*)(wsb + 104ull * NN);               // NN
    int*   gcur     = (int*)(wsb + 108ull * NN);               // pad 16 B
    int2*  edges    = (int2*)(wsb + 108ull * NN + 16);         // NE int2 (12.8 MB)
    ushort* hb      = (ushort*)(wsb + 108ull * NN + 16 + 8ull * NE); // NN*DD bf16
    float* x1       = out;   // layer-1 output in d_out (overwritten by layer 2)

    zero_k<<<(8 * NN + 255) / 256, 256, 0, stream>>>(hist8, gcur);
    hist_k<<<NE / 256, 256, 0, stream>>>(dstp, ew, hist8);
    reduce_assign<<<(NN + 255) / 256, 256, 0, stream>>>(hist8, deg, hist, rowstart,
                                                        cursor8, gcur);
    csr_scatter<<<NE / 256, 256, 0, stream>>>(srcp, dstp, ew, deg, cursor8, edges);

    const int gemm_blocks = (NN + 63) / 64;
    const int gath_blocks = NN / 8;

    // ---- layer 1 ----
    gemm_nn<<<gemm_blocks, 256, 0, stream>>>(feat, W1, hb, NN);
    gather_finalize<<<gath_blocks, 256, 0, stream>>>(hb, edges, rowstart, hist, deg, b1, a1, x1);
    // ---- layer 2 ----
    gemm_nn<<<gemm_blocks, 256, 0, stream>>>(x1, W2, hb, NN);
    gather_finalize<<<gath_blocks, 256, 0, stream>>>(hb, edges, rowstart, hist, deg, b2, a2, out);
}

// Round 6
// 436.873 us; speedup vs baseline: 3.9934x; 1.2877x over previous
//
#include <hip/hip_runtime.h>
#include <cstdint>

#define NN 100000
#define NE 1600000
#define DD 128
#define NB 250            // node buckets
#define BSZ 400           // nodes per bucket  (NB*BSZ == NN)

typedef unsigned int uint;
typedef unsigned short ushort;

// fp32 -> bf16 bits, round-to-nearest-even
__device__ inline uint f2bf(float f) {
    uint u = __float_as_uint(f);
    return (u + 0x7fffu + ((u >> 16) & 1u)) >> 16;
}

// ---------------- CSR build: bucketed counting sort ----------------

__global__ __launch_bounds__(256) void zero_bc(uint* __restrict__ bc) {
    if (threadIdx.x < NB) bc[threadIdx.x] = 0u;
}

// Pass 1: bucket histogram, LDS-aggregated. 256 thr x 32 edges = 8192/block.
__global__ __launch_bounds__(256) void bucket_hist(const int* __restrict__ dst,
                                                   uint* __restrict__ bc) {
    __shared__ uint h[NB];
    int tid = threadIdx.x;
    if (tid < NB) h[tid] = 0u;
    __syncthreads();
    int e0 = blockIdx.x * 8192 + tid;
#pragma unroll
    for (int k = 0; k < 32; ++k) {
        int e = e0 + 256 * k;
        if (e < NE) atomicAdd(&h[(uint)dst[e] / BSZ], 1u);
    }
    __syncthreads();
    if (tid < NB && h[tid]) atomicAdd(&bc[tid], h[tid]);
}

// Pass 2: exclusive prefix over NB bucket counts (single block, wave 0).
__global__ __launch_bounds__(256) void bucket_prefix(const uint* __restrict__ bc,
                                                     uint* __restrict__ bbase,
                                                     uint* __restrict__ bcur) {
    int lane = threadIdx.x;
    if (lane < 64) {
        uint v[4], s = 0;
#pragma unroll
        for (int k = 0; k < 4; ++k) {
            int i = lane * 4 + k;
            v[k] = (i < NB) ? bc[i] : 0u;
            s += v[k];
        }
        uint inc = s;
#pragma unroll
        for (int d = 1; d < 64; d <<= 1) {
            uint t = __shfl_up(inc, (unsigned)d, 64);
            if (lane >= d) inc += t;
        }
        uint run = inc - s;      // exclusive chunk base
#pragma unroll
        for (int k = 0; k < 4; ++k) {
            int i = lane * 4 + k;
            if (i < NB) { bbase[i] = run; bcur[i] = run; run += v[k]; }
        }
        if (lane == 63) bbase[NB] = run;   // == NE
    }
}

// Pass 3: block-aggregated append into bucket regions.
// payload: {src, (dstLocal<<23) | wq23}
__global__ __launch_bounds__(256) void bucket_append(const int* __restrict__ src,
                                                     const int* __restrict__ dst,
                                                     const float* __restrict__ w,
                                                     uint* __restrict__ bcur,
                                                     int2* __restrict__ etmp) {
    __shared__ uint h[NB];
    __shared__ uint res[NB];
    int tid = threadIdx.x;
    if (tid < NB) h[tid] = 0u;
    __syncthreads();
    int e0 = blockIdx.x * 4096 + tid;
    uint rank[16], bkt[16];
#pragma unroll
    for (int k = 0; k < 16; ++k) {
        int e = e0 + 256 * k;
        if (e < NE) {
            uint b = (uint)dst[e] / BSZ;
            bkt[k] = b;
            rank[k] = atomicAdd(&h[b], 1u);
        } else bkt[k] = 0xffffffffu;
    }
    __syncthreads();
    if (tid < NB) res[tid] = h[tid] ? atomicAdd(&bcur[tid], h[tid]) : 0u;
    __syncthreads();
#pragma unroll
    for (int k = 0; k < 16; ++k) {
        if (bkt[k] != 0xffffffffu) {
            int e = e0 + 256 * k;
            uint dl = (uint)dst[e] - bkt[k] * BSZ;
            uint wq = (uint)(w[e] * 8388608.0f);
            if (wq > 8388607u) wq = 8388607u;
            etmp[res[bkt[k]] + rank[k]] = make_int2(src[e], (int)((dl << 23) | wq));
        }
    }
}

// Pass 4: per-bucket (block-exclusive): deg -> dis, per-node scan -> rowstart,
// exact placement with norm' = w * dis[dst].
__global__ __launch_bounds__(256) void bucket_build(const int2* __restrict__ etmp,
                                                    const uint* __restrict__ bbase,
                                                    float* __restrict__ dis,
                                                    int* __restrict__ hist_g,
                                                    int* __restrict__ rowstart,
                                                    int2* __restrict__ edges) {
    __shared__ float wdeg[BSZ];
    __shared__ uint  cnt[BSZ];
    __shared__ uint  cur[BSZ];
    __shared__ float disl[BSZ];
    int tid = threadIdx.x;
    int b = blockIdx.x;
    int n0 = b * BSZ;
    for (int i = tid; i < BSZ; i += 256) { wdeg[i] = 0.f; cnt[i] = 0u; }
    __syncthreads();
    uint base = bbase[b], end = bbase[b + 1];
    for (uint i = base + tid; i < end; i += 256) {
        uint y = (uint)etmp[i].y;
        uint dl = y >> 23;
        float wv = (float)(y & 0x7fffffu) * (1.0f / 8388608.0f);
        atomicAdd(&wdeg[dl], wv);
        atomicAdd(&cnt[dl], 1u);
    }
    __syncthreads();
    // exclusive scan of cnt[0..BSZ) in wave 0 (chunk of 7 per lane; 7*64=448>=400)
    if (tid < 64) {
        uint v[7], s = 0;
#pragma unroll
        for (int k = 0; k < 7; ++k) {
            int i = tid * 7 + k;
            v[k] = (i < BSZ) ? cnt[i] : 0u;
            s += v[k];
        }
        uint inc = s;
#pragma unroll
        for (int d = 1; d < 64; d <<= 1) {
            uint t = __shfl_up(inc, (unsigned)d, 64);
            if (tid >= d) inc += t;
        }
        uint run = inc - s;
#pragma unroll
        for (int k = 0; k < 7; ++k) {
            int i = tid * 7 + k;
            if (i < BSZ) { cur[i] = run; run += v[k]; }
        }
    }
    __syncthreads();
    // per-node outputs (rowstart snapshot BEFORE placement mutates cur)
    for (int i = tid; i < BSZ; i += 256) {
        float ds = rsqrtf(1.0f + wdeg[i]);
        disl[i] = ds;
        dis[n0 + i] = ds;
        hist_g[n0 + i] = (int)cnt[i];
        rowstart[n0 + i] = (int)(base + cur[i]);
    }
    __syncthreads();
    // placement into block-exclusive region [base, end)
    for (uint i = base + tid; i < end; i += 256) {
        int2 e = etmp[i];
        uint y = (uint)e.y;
        uint dl = y >> 23;
        float wv = (float)(y & 0x7fffffu) * (1.0f / 8388608.0f);
        uint p = atomicAdd(&cur[dl], 1u);
        float nrm = wv * disl[dl];
        edges[base + p] = make_int2(e.x, __float_as_int(nrm));
    }
}

// ---------------- GEMM: HB[r,:] = bf16( (X[r,:] @ W) * dis[r] ) ----------------
__global__ __launch_bounds__(256) void gemm_nn(const float* __restrict__ X,
                                               const float* __restrict__ W,
                                               const float* __restrict__ dis,
                                               ushort* __restrict__ HB, int nrows) {
    __shared__ float Ws[DD * DD];          // 64 KB
    int tid = threadIdx.x;
    const float4* W4 = (const float4*)W;
    float4* Ws4 = (float4*)Ws;
#pragma unroll
    for (int i = 0; i < 16; ++i) Ws4[tid + 256 * i] = W4[tid + 256 * i];
    __syncthreads();

    int row0 = blockIdx.x * 64;
    int tx = tid & 15;
    int ty = tid >> 4;

    int rows[4];
#pragma unroll
    for (int r = 0; r < 4; ++r) {
        int g = row0 + ty * 4 + r;
        rows[r] = g < nrows ? g : (nrows - 1);
    }

    float acc[4][8];
#pragma unroll
    for (int r = 0; r < 4; ++r)
#pragma unroll
        for (int j = 0; j < 8; ++j) acc[r][j] = 0.f;

    for (int k = 0; k < DD; k += 4) {
        float4 xv[4];
#pragma unroll
        for (int r = 0; r < 4; ++r)
            xv[r] = *(const float4*)&X[(long)rows[r] * DD + k];
#pragma unroll
        for (int kk = 0; kk < 4; ++kk) {
            float4 w0 = *(const float4*)&Ws[(k + kk) * DD + tx * 8];
            float4 w1 = *(const float4*)&Ws[(k + kk) * DD + tx * 8 + 4];
#pragma unroll
            for (int r = 0; r < 4; ++r) {
                float xs = (&xv[r].x)[kk];
                acc[r][0] += xs * w0.x;
                acc[r][1] += xs * w0.y;
                acc[r][2] += xs * w0.z;
                acc[r][3] += xs * w0.w;
                acc[r][4] += xs * w1.x;
                acc[r][5] += xs * w1.y;
                acc[r][6] += xs * w1.z;
                acc[r][7] += xs * w1.w;
            }
        }
    }

#pragma unroll
    for (int r = 0; r < 4; ++r) {
        int g = row0 + ty * 4 + r;
        if (g < nrows) {
            float ds = dis[g];
            uint4 o;
            o.x = f2bf(acc[r][0] * ds) | (f2bf(acc[r][1] * ds) << 16);
            o.y = f2bf(acc[r][2] * ds) | (f2bf(acc[r][3] * ds) << 16);
            o.z = f2bf(acc[r][4] * ds) | (f2bf(acc[r][5] * ds) << 16);
            o.w = f2bf(acc[r][6] * ds) | (f2bf(acc[r][7] * ds) << 16);
            *(uint4*)&HB[(size_t)g * DD + tx * 8] = o;
        }
    }
}

// decode 4 bf16 (uint2) -> float4
__device__ inline float4 bf4(uint2 u) {
    float4 f;
    f.x = __uint_as_float(u.x << 16);
    f.y = __uint_as_float(u.x & 0xffff0000u);
    f.z = __uint_as_float(u.y << 16);
    f.w = __uint_as_float(u.y & 0xffff0000u);
    return f;
}

// ---------------- fused gather + self-loop + bias + PReLU ----------------
// lane = 4 channels; 32 lanes/node; 8 nodes per 256-block.
// hb rows are pre-scaled by dis[src]; edge carries norm' = w * dis[dst];
// self term = hb_row(node) * dis[node]  (== h/deg).
__global__ __launch_bounds__(256) void gather_finalize(const ushort* __restrict__ hb,
                                                       const int2* __restrict__ edges,
                                                       const int* __restrict__ rowstart,
                                                       const int* __restrict__ hist,
                                                       const float* __restrict__ dis,
                                                       const float* __restrict__ b,
                                                       const float* __restrict__ a,
                                                       float* __restrict__ xout) {
    int tid = threadIdx.x;
    int lane = tid & 31;                      // channels lane*4 .. lane*4+3
    int node = blockIdx.x * 8 + (tid >> 5);   // NN % 8 == 0

    int start = rowstart[node];
    int cnt = hist[node];
    float ds = dis[node];

    const uint2* hrow = (const uint2*)(hb + (size_t)node * DD) + lane;
    float4 self = bf4(*hrow);
    float4 acc0, acc1;
    acc0.x = self.x * ds; acc0.y = self.y * ds;
    acc0.z = self.z * ds; acc0.w = self.w * ds;
    acc1 = make_float4(0.f, 0.f, 0.f, 0.f);

    int j = 0;
    for (; j + 4 <= cnt; j += 4) {
        int2 e0 = edges[start + j];
        int2 e1 = edges[start + j + 1];
        int2 e2 = edges[start + j + 2];
        int2 e3 = edges[start + j + 3];
        uint2 u0 = *((const uint2*)(hb + (size_t)e0.x * DD) + lane);
        uint2 u1 = *((const uint2*)(hb + (size_t)e1.x * DD) + lane);
        uint2 u2 = *((const uint2*)(hb + (size_t)e2.x * DD) + lane);
        uint2 u3 = *((const uint2*)(hb + (size_t)e3.x * DD) + lane);
        float n0 = __int_as_float(e0.y), n1 = __int_as_float(e1.y);
        float n2 = __int_as_float(e2.y), n3 = __int_as_float(e3.y);
        float4 v0 = bf4(u0), v1 = bf4(u1), v2 = bf4(u2), v3 = bf4(u3);
        acc0.x += v0.x * n0; acc0.y += v0.y * n0; acc0.z += v0.z * n0; acc0.w += v0.w * n0;
        acc1.x += v1.x * n1; acc1.y += v1.y * n1; acc1.z += v1.z * n1; acc1.w += v1.w * n1;
        acc0.x += v2.x * n2; acc0.y += v2.y * n2; acc0.z += v2.z * n2; acc0.w += v2.w * n2;
        acc1.x += v3.x * n3; acc1.y += v3.y * n3; acc1.z += v3.z * n3; acc1.w += v3.w * n3;
    }
    for (; j < cnt; ++j) {
        int2 e = edges[start + j];
        uint2 u = *((const uint2*)(hb + (size_t)e.x * DD) + lane);
        float n = __int_as_float(e.y);
        float4 v = bf4(u);
        acc0.x += v.x * n; acc0.y += v.y * n; acc0.z += v.z * n; acc0.w += v.w * n;
    }

    float4 bb = ((const float4*)b)[lane];
    float4 aa = ((const float4*)a)[lane];
    float4 r;
    r.x = acc0.x + acc1.x + bb.x;
    r.y = acc0.y + acc1.y + bb.y;
    r.z = acc0.z + acc1.z + bb.z;
    r.w = acc0.w + acc1.w + bb.w;
    r.x = r.x >= 0.f ? r.x : aa.x * r.x;
    r.y = r.y >= 0.f ? r.y : aa.y * r.y;
    r.z = r.z >= 0.f ? r.z : aa.z * r.z;
    r.w = r.w >= 0.f ? r.w : aa.w * r.w;
    ((float4*)xout)[(size_t)node * 32 + lane] = r;
}

extern "C" void kernel_launch(void* const* d_in, const int* in_sizes, int n_in,
                              void* d_out, int out_size, void* d_ws, size_t ws_size,
                              hipStream_t stream) {
    const float* feat = (const float*)d_in[0];
    const int*   ei   = (const int*)d_in[1];     // [2, NE]
    const float* ew   = (const float*)d_in[2];
    const float* W1   = (const float*)d_in[3];
    const float* b1   = (const float*)d_in[4];
    const float* a1   = (const float*)d_in[5];
    const float* W2   = (const float*)d_in[6];
    const float* b2   = (const float*)d_in[7];
    const float* a2   = (const float*)d_in[8];
    float* out = (float*)d_out;

    const int* srcp = ei;
    const int* dstp = ei + NE;

    // workspace carve (bytes) — ~53 MB
    char* wsb = (char*)d_ws;
    size_t off = 0;
    uint* bc     = (uint*)(wsb + off); off += 4096;                 // NB counts
    uint* bbase  = (uint*)(wsb + off); off += 4096;                 // NB+1
    uint* bcur   = (uint*)(wsb + off); off += 4096;                 // NB
    float* dis   = (float*)(wsb + off); off += 4ull * NN;           // NN
    int* hist    = (int*)(wsb + off); off += 4ull * NN;             // NN
    int* rowstart= (int*)(wsb + off); off += 4ull * NN;             // NN
    int2* etmp   = (int2*)(wsb + off); off += 8ull * NE;            // NE
    int2* edges  = (int2*)(wsb + off); off += 8ull * NE;            // NE
    ushort* hb   = (ushort*)(wsb + off); off += 2ull * NN * DD;     // NN*DD bf16
    float* x1    = out;   // layer-1 output in d_out (overwritten by layer 2)

    // ---- CSR build (bucketed counting sort) ----
    zero_bc<<<1, 256, 0, stream>>>(bc);
    bucket_hist<<<(NE + 8191) / 8192, 256, 0, stream>>>(dstp, bc);
    bucket_prefix<<<1, 256, 0, stream>>>(bc, bbase, bcur);
    bucket_append<<<(NE + 4095) / 4096, 256, 0, stream>>>(srcp, dstp, ew, bcur, etmp);
    bucket_build<<<NB, 256, 0, stream>>>(etmp, bbase, dis, hist, rowstart, edges);

    const int gemm_blocks = (NN + 63) / 64;
    const int gath_blocks = NN / 8;

    // ---- layer 1 ----
    gemm_nn<<<gemm_blocks, 256, 0, stream>>>(feat, W1, dis, hb, NN);
    gather_finalize<<<gath_blocks, 256, 0, stream>>>(hb, edges, rowstart, hist, dis, b1, a1, x1);
    // ---- layer 2 ----
    gemm_nn<<<gemm_blocks, 256, 0, stream>>>(x1, W2, dis, hb, NN);
    gather_finalize<<<gath_blocks, 256, 0, stream>>>(hb, edges, rowstart, hist, dis, b2, a2, out);
}

// Round 7
// 375.299 us; speedup vs baseline: 4.6486x; 1.1641x over previous
//
#include <hip/hip_runtime.h>
#include <cstdint>

#define NN 100000
#define NE 1600000
#define DD 128
#define NB 250            // node buckets
#define BSZ 400           // nodes per bucket  (NB*BSZ == NN)

typedef unsigned int uint;
typedef unsigned short ushort;

typedef __attribute__((ext_vector_type(8))) short short8;   // 8 bf16 (4 VGPRs)
typedef __attribute__((ext_vector_type(4))) float floatx4;  // MFMA acc

// fp32 -> bf16 bits, round-to-nearest-even
__device__ inline uint f2bf(float f) {
    uint u = __float_as_uint(f);
    return (u + 0x7fffu + ((u >> 16) & 1u)) >> 16;
}

// ---------------- CSR build: bucketed counting sort ----------------

__global__ __launch_bounds__(256) void zero_bc(uint* __restrict__ bc) {
    if (threadIdx.x < NB) bc[threadIdx.x] = 0u;
}

// Pass 1: bucket histogram, LDS-aggregated. 256 thr x 32 edges = 8192/block.
__global__ __launch_bounds__(256) void bucket_hist(const int* __restrict__ dst,
                                                   uint* __restrict__ bc) {
    __shared__ uint h[NB];
    int tid = threadIdx.x;
    if (tid < NB) h[tid] = 0u;
    __syncthreads();
    int e0 = blockIdx.x * 8192 + tid;
#pragma unroll
    for (int k = 0; k < 32; ++k) {
        int e = e0 + 256 * k;
        if (e < NE) atomicAdd(&h[(uint)dst[e] / BSZ], 1u);
    }
    __syncthreads();
    if (tid < NB && h[tid]) atomicAdd(&bc[tid], h[tid]);
}

// Pass 2: exclusive prefix over NB bucket counts (single block, wave 0).
__global__ __launch_bounds__(256) void bucket_prefix(const uint* __restrict__ bc,
                                                     uint* __restrict__ bbase,
                                                     uint* __restrict__ bcur) {
    int lane = threadIdx.x;
    if (lane < 64) {
        uint v[4], s = 0;
#pragma unroll
        for (int k = 0; k < 4; ++k) {
            int i = lane * 4 + k;
            v[k] = (i < NB) ? bc[i] : 0u;
            s += v[k];
        }
        uint inc = s;
#pragma unroll
        for (int d = 1; d < 64; d <<= 1) {
            uint t = __shfl_up(inc, (unsigned)d, 64);
            if (lane >= d) inc += t;
        }
        uint run = inc - s;      // exclusive chunk base
#pragma unroll
        for (int k = 0; k < 4; ++k) {
            int i = lane * 4 + k;
            if (i < NB) { bbase[i] = run; bcur[i] = run; run += v[k]; }
        }
        if (lane == 63) bbase[NB] = run;   // == NE
    }
}

// Pass 3: block-aggregated append into bucket regions.
// payload: {src, (dstLocal<<23) | wq23}
__global__ __launch_bounds__(256) void bucket_append(const int* __restrict__ src,
                                                     const int* __restrict__ dst,
                                                     const float* __restrict__ w,
                                                     uint* __restrict__ bcur,
                                                     int2* __restrict__ etmp) {
    __shared__ uint h[NB];
    __shared__ uint res[NB];
    int tid = threadIdx.x;
    if (tid < NB) h[tid] = 0u;
    __syncthreads();
    int e0 = blockIdx.x * 4096 + tid;
    uint rank[16], bkt[16];
#pragma unroll
    for (int k = 0; k < 16; ++k) {
        int e = e0 + 256 * k;
        if (e < NE) {
            uint b = (uint)dst[e] / BSZ;
            bkt[k] = b;
            rank[k] = atomicAdd(&h[b], 1u);
        } else bkt[k] = 0xffffffffu;
    }
    __syncthreads();
    if (tid < NB) res[tid] = h[tid] ? atomicAdd(&bcur[tid], h[tid]) : 0u;
    __syncthreads();
#pragma unroll
    for (int k = 0; k < 16; ++k) {
        if (bkt[k] != 0xffffffffu) {
            int e = e0 + 256 * k;
            uint dl = (uint)dst[e] - bkt[k] * BSZ;
            uint wq = (uint)(w[e] * 8388608.0f);
            if (wq > 8388607u) wq = 8388607u;
            etmp[res[bkt[k]] + rank[k]] = make_int2(src[e], (int)((dl << 23) | wq));
        }
    }
}

// Pass 4: per-bucket (block-exclusive): deg -> dis, per-node scan -> rowstart,
// exact placement with norm' = w * dis[dst].
__global__ __launch_bounds__(256) void bucket_build(const int2* __restrict__ etmp,
                                                    const uint* __restrict__ bbase,
                                                    float* __restrict__ dis,
                                                    int* __restrict__ hist_g,
                                                    int* __restrict__ rowstart,
                                                    int2* __restrict__ edges) {
    __shared__ float wdeg[BSZ];
    __shared__ uint  cnt[BSZ];
    __shared__ uint  cur[BSZ];
    __shared__ float disl[BSZ];
    int tid = threadIdx.x;
    int b = blockIdx.x;
    int n0 = b * BSZ;
    for (int i = tid; i < BSZ; i += 256) { wdeg[i] = 0.f; cnt[i] = 0u; }
    __syncthreads();
    uint base = bbase[b], end = bbase[b + 1];
    for (uint i = base + tid; i < end; i += 256) {
        uint y = (uint)etmp[i].y;
        uint dl = y >> 23;
        float wv = (float)(y & 0x7fffffu) * (1.0f / 8388608.0f);
        atomicAdd(&wdeg[dl], wv);
        atomicAdd(&cnt[dl], 1u);
    }
    __syncthreads();
    // exclusive scan of cnt[0..BSZ) in wave 0 (chunk of 7 per lane; 7*64=448>=400)
    if (tid < 64) {
        uint v[7], s = 0;
#pragma unroll
        for (int k = 0; k < 7; ++k) {
            int i = tid * 7 + k;
            v[k] = (i < BSZ) ? cnt[i] : 0u;
            s += v[k];
        }
        uint inc = s;
#pragma unroll
        for (int d = 1; d < 64; d <<= 1) {
            uint t = __shfl_up(inc, (unsigned)d, 64);
            if (tid >= d) inc += t;
        }
        uint run = inc - s;
#pragma unroll
        for (int k = 0; k < 7; ++k) {
            int i = tid * 7 + k;
            if (i < BSZ) { cur[i] = run; run += v[k]; }
        }
    }
    __syncthreads();
    // per-node outputs (rowstart snapshot BEFORE placement mutates cur)
    for (int i = tid; i < BSZ; i += 256) {
        float ds = rsqrtf(1.0f + wdeg[i]);
        disl[i] = ds;
        dis[n0 + i] = ds;
        hist_g[n0 + i] = (int)cnt[i];
        rowstart[n0 + i] = (int)(base + cur[i]);
    }
    __syncthreads();
    // placement into block-exclusive region [base, end)
    for (uint i = base + tid; i < end; i += 256) {
        int2 e = etmp[i];
        uint y = (uint)e.y;
        uint dl = y >> 23;
        float wv = (float)(y & 0x7fffffu) * (1.0f / 8388608.0f);
        uint p = atomicAdd(&cur[dl], 1u);
        float nrm = wv * disl[dl];
        edges[base + p] = make_int2(e.x, __float_as_int(nrm));
    }
}

// ---------------- MFMA GEMM: HB[r,:] = bf16( (X[r,:] @ W) * dis[r] ) ----------------
// Block = 256 thr = 4 waves; wave computes 16 rows x 128 cols via 16x16x32 bf16 MFMA.
// W staged transposed in LDS (Wt[n][k], bf16, stride 136 -> 16B-aligned ds_read_b128,
// bank aliasing <= 2-way which is free).
// Verified layouts (m89/m91): A: m=lane&15, k=(lane>>4)*8+j; B: n=lane&15, same k;
// D: col=lane&15, row=(lane>>4)*4+reg.
#define WTS 136
__global__ __launch_bounds__(256) void gemm_mfma(const float* __restrict__ X,
                                                 const float* __restrict__ W,
                                                 const float* __restrict__ dis,
                                                 ushort* __restrict__ HB, int nrows) {
    __shared__ ushort Wt[DD * WTS];        // 34 KB
    int tid = threadIdx.x;
    // stage Wt[n][k] = bf16(W[k*128+n]); coalesced float4 reads of W
#pragma unroll
    for (int it = 0; it < 16; ++it) {
        int flat = (tid + it * 256) * 4;   // k*128 + n
        int k = flat >> 7, n = flat & 127;
        float4 wv = *(const float4*)&W[flat];
        Wt[(n + 0) * WTS + k] = (ushort)f2bf(wv.x);
        Wt[(n + 1) * WTS + k] = (ushort)f2bf(wv.y);
        Wt[(n + 2) * WTS + k] = (ushort)f2bf(wv.z);
        Wt[(n + 3) * WTS + k] = (ushort)f2bf(wv.w);
    }
    __syncthreads();

    int wave = tid >> 6, lane = tid & 63;
    int q = lane >> 4, l16 = lane & 15;
    int row0 = blockIdx.x * 64 + wave * 16;

    // A fragments: full K=128 of this lane's row (4 ksteps x 8 bf16)
    int arow = row0 + l16;
    if (arow >= nrows) arow = nrows - 1;
    const float* xr = X + (size_t)arow * DD + q * 8;
    short8 afr[4];
#pragma unroll
    for (int ks = 0; ks < 4; ++ks) {
        float4 f0 = *(const float4*)(xr + ks * 32);
        float4 f1 = *(const float4*)(xr + ks * 32 + 4);
        uint4 u;
        u.x = f2bf(f0.x) | (f2bf(f0.y) << 16);
        u.y = f2bf(f0.z) | (f2bf(f0.w) << 16);
        u.z = f2bf(f1.x) | (f2bf(f1.y) << 16);
        u.w = f2bf(f1.z) | (f2bf(f1.w) << 16);
        afr[ks] = __builtin_bit_cast(short8, u);
    }

    floatx4 acc[8];
#pragma unroll
    for (int ct = 0; ct < 8; ++ct) acc[ct] = (floatx4)(0.0f);

#pragma unroll
    for (int ct = 0; ct < 8; ++ct) {
        const ushort* wp = &Wt[(ct * 16 + l16) * WTS + q * 8];
#pragma unroll
        for (int ks = 0; ks < 4; ++ks) {
            short8 bfr = *(const short8*)(wp + ks * 32);
            acc[ct] = __builtin_amdgcn_mfma_f32_16x16x32_bf16(afr[ks], bfr, acc[ct], 0, 0, 0);
        }
    }

    // epilogue: row = row0 + q*4 + reg, col = ct*16 + l16 ; scale by dis[row]
#pragma unroll
    for (int reg = 0; reg < 4; ++reg) {
        int r = row0 + q * 4 + reg;
        if (r < nrows) {
            float ds = dis[r];
            ushort* orow = HB + (size_t)r * DD + l16;
#pragma unroll
            for (int ct = 0; ct < 8; ++ct)
                orow[ct * 16] = (ushort)f2bf(acc[ct][reg] * ds);
        }
    }
}

// decode 4 bf16 (uint2) -> float4
__device__ inline float4 bf4(uint2 u) {
    float4 f;
    f.x = __uint_as_float(u.x << 16);
    f.y = __uint_as_float(u.x & 0xffff0000u);
    f.z = __uint_as_float(u.y << 16);
    f.w = __uint_as_float(u.y & 0xffff0000u);
    return f;
}

// ---------------- fused gather + self-loop + bias + PReLU ----------------
// lane = 4 channels; 32 lanes/node; 8 nodes per 256-block.
// hb rows are pre-scaled by dis[src]; edge carries norm' = w * dis[dst];
// self term = hb_row(node) * dis[node]  (== h/deg).
__global__ __launch_bounds__(256) void gather_finalize(const ushort* __restrict__ hb,
                                                       const int2* __restrict__ edges,
                                                       const int* __restrict__ rowstart,
                                                       const int* __restrict__ hist,
                                                       const float* __restrict__ dis,
                                                       const float* __restrict__ b,
                                                       const float* __restrict__ a,
                                                       float* __restrict__ xout) {
    int tid = threadIdx.x;
    int lane = tid & 31;                      // channels lane*4 .. lane*4+3
    int node = blockIdx.x * 8 + (tid >> 5);   // NN % 8 == 0

    int start = rowstart[node];
    int cnt = hist[node];
    float ds = dis[node];

    const uint2* hrow = (const uint2*)(hb + (size_t)node * DD) + lane;
    float4 self = bf4(*hrow);
    float4 acc0, acc1;
    acc0.x = self.x * ds; acc0.y = self.y * ds;
    acc0.z = self.z * ds; acc0.w = self.w * ds;
    acc1 = make_float4(0.f, 0.f, 0.f, 0.f);

    int j = 0;
    for (; j + 4 <= cnt; j += 4) {
        int2 e0 = edges[start + j];
        int2 e1 = edges[start + j + 1];
        int2 e2 = edges[start + j + 2];
        int2 e3 = edges[start + j + 3];
        uint2 u0 = *((const uint2*)(hb + (size_t)e0.x * DD) + lane);
        uint2 u1 = *((const uint2*)(hb + (size_t)e1.x * DD) + lane);
        uint2 u2 = *((const uint2*)(hb + (size_t)e2.x * DD) + lane);
        uint2 u3 = *((const uint2*)(hb + (size_t)e3.x * DD) + lane);
        float n0 = __int_as_float(e0.y), n1 = __int_as_float(e1.y);
        float n2 = __int_as_float(e2.y), n3 = __int_as_float(e3.y);
        float4 v0 = bf4(u0), v1 = bf4(u1), v2 = bf4(u2), v3 = bf4(u3);
        acc0.x += v0.x * n0; acc0.y += v0.y * n0; acc0.z += v0.z * n0; acc0.w += v0.w * n0;
        acc1.x += v1.x * n1; acc1.y += v1.y * n1; acc1.z += v1.z * n1; acc1.w += v1.w * n1;
        acc0.x += v2.x * n2; acc0.y += v2.y * n2; acc0.z += v2.z * n2; acc0.w += v2.w * n2;
        acc1.x += v3.x * n3; acc1.y += v3.y * n3; acc1.z += v3.z * n3; acc1.w += v3.w * n3;
    }
    for (; j < cnt; ++j) {
        int2 e = edges[start + j];
        uint2 u = *((const uint2*)(hb + (size_t)e.x * DD) + lane);
        float n = __int_as_float(e.y);
        float4 v = bf4(u);
        acc0.x += v.x * n; acc0.y += v.y * n; acc0.z += v.z * n; acc0.w += v.w * n;
    }

    float4 bb = ((const float4*)b)[lane];
    float4 aa = ((const float4*)a)[lane];
    float4 r;
    r.x = acc0.x + acc1.x + bb.x;
    r.y = acc0.y + acc1.y + bb.y;
    r.z = acc0.z + acc1.z + bb.z;
    r.w = acc0.w + acc1.w + bb.w;
    r.x = r.x >= 0.f ? r.x : aa.x * r.x;
    r.y = r.y >= 0.f ? r.y : aa.y * r.y;
    r.z = r.z >= 0.f ? r.z : aa.z * r.z;
    r.w = r.w >= 0.f ? r.w : aa.w * r.w;
    ((float4*)xout)[(size_t)node * 32 + lane] = r;
}

extern "C" void kernel_launch(void* const* d_in, const int* in_sizes, int n_in,
                              void* d_out, int out_size, void* d_ws, size_t ws_size,
                              hipStream_t stream) {
    const float* feat = (const float*)d_in[0];
    const int*   ei   = (const int*)d_in[1];     // [2, NE]
    const float* ew   = (const float*)d_in[2];
    const float* W1   = (const float*)d_in[3];
    const float* b1   = (const float*)d_in[4];
    const float* a1   = (const float*)d_in[5];
    const float* W2   = (const float*)d_in[6];
    const float* b2   = (const float*)d_in[7];
    const float* a2   = (const float*)d_in[8];
    float* out = (float*)d_out;

    const int* srcp = ei;
    const int* dstp = ei + NE;

    // workspace carve (bytes) — ~53 MB
    char* wsb = (char*)d_ws;
    size_t off = 0;
    uint* bc     = (uint*)(wsb + off); off += 4096;                 // NB counts
    uint* bbase  = (uint*)(wsb + off); off += 4096;                 // NB+1
    uint* bcur   = (uint*)(wsb + off); off += 4096;                 // NB
    float* dis   = (float*)(wsb + off); off += 4ull * NN;           // NN
    int* hist    = (int*)(wsb + off); off += 4ull * NN;             // NN
    int* rowstart= (int*)(wsb + off); off += 4ull * NN;             // NN
    int2* etmp   = (int2*)(wsb + off); off += 8ull * NE;            // NE
    int2* edges  = (int2*)(wsb + off); off += 8ull * NE;            // NE
    ushort* hb   = (ushort*)(wsb + off); off += 2ull * NN * DD;     // NN*DD bf16
    float* x1    = out;   // layer-1 output in d_out (overwritten by layer 2)

    // ---- CSR build (bucketed counting sort) ----
    zero_bc<<<1, 256, 0, stream>>>(bc);
    bucket_hist<<<(NE + 8191) / 8192, 256, 0, stream>>>(dstp, bc);
    bucket_prefix<<<1, 256, 0, stream>>>(bc, bbase, bcur);
    bucket_append<<<(NE + 4095) / 4096, 256, 0, stream>>>(srcp, dstp, ew, bcur, etmp);
    bucket_build<<<NB, 256, 0, stream>>>(etmp, bbase, dis, hist, rowstart, edges);

    const int gemm_blocks = (NN + 63) / 64;
    const int gath_blocks = NN / 8;

    // ---- layer 1 ----
    gemm_mfma<<<gemm_blocks, 256, 0, stream>>>(feat, W1, dis, hb, NN);
    gather_finalize<<<gath_blocks, 256, 0, stream>>>(hb, edges, rowstart, hist, dis, b1, a1, x1);
    // ---- layer 2 ----
    gemm_mfma<<<gemm_blocks, 256, 0, stream>>>(x1, W2, dis, hb, NN);
    gather_finalize<<<gath_blocks, 256, 0, stream>>>(hb, edges, rowstart, hist, dis, b2, a2, out);
}

// Round 8
// 374.292 us; speedup vs baseline: 4.6611x; 1.0027x over previous
//
#include <hip/hip_runtime.h>
#include <cstdint>

#define NN 100000
#define NE 1600000
#define DD 128
#define NB 250            // node buckets
#define BSZ 400           // nodes per bucket  (NB*BSZ == NN)

typedef unsigned int uint;
typedef unsigned short ushort;
typedef unsigned long long u64;

typedef __attribute__((ext_vector_type(8))) short short8;   // 8 bf16 (4 VGPRs)
typedef __attribute__((ext_vector_type(4))) float floatx4;  // MFMA acc

// fp32 -> bf16 bits, round-to-nearest-even
__device__ inline uint f2bf(float f) {
    uint u = __float_as_uint(f);
    return (u + 0x7fffu + ((u >> 16) & 1u)) >> 16;
}

// ---------------- CSR build: bucketed counting sort ----------------

__global__ __launch_bounds__(256) void zero_bc(uint* __restrict__ bc) {
    if (threadIdx.x < NB) bc[threadIdx.x] = 0u;
}

// Pass 1: bucket histogram, LDS-aggregated. 256 thr x 32 edges = 8192/block.
__global__ __launch_bounds__(256) void bucket_hist(const int* __restrict__ dst,
                                                   uint* __restrict__ bc) {
    __shared__ uint h[NB];
    int tid = threadIdx.x;
    if (tid < NB) h[tid] = 0u;
    __syncthreads();
    int e0 = blockIdx.x * 8192 + tid;
#pragma unroll
    for (int k = 0; k < 32; ++k) {
        int e = e0 + 256 * k;
        if (e < NE) atomicAdd(&h[(uint)dst[e] / BSZ], 1u);
    }
    __syncthreads();
    if (tid < NB && h[tid]) atomicAdd(&bc[tid], h[tid]);
}

// Pass 2: exclusive prefix over NB bucket counts (single block, wave 0).
__global__ __launch_bounds__(256) void bucket_prefix(const uint* __restrict__ bc,
                                                     uint* __restrict__ bbase,
                                                     uint* __restrict__ bcur) {
    int lane = threadIdx.x;
    if (lane < 64) {
        uint v[4], s = 0;
#pragma unroll
        for (int k = 0; k < 4; ++k) {
            int i = lane * 4 + k;
            v[k] = (i < NB) ? bc[i] : 0u;
            s += v[k];
        }
        uint inc = s;
#pragma unroll
        for (int d = 1; d < 64; d <<= 1) {
            uint t = __shfl_up(inc, (unsigned)d, 64);
            if (lane >= d) inc += t;
        }
        uint run = inc - s;      // exclusive chunk base
#pragma unroll
        for (int k = 0; k < 4; ++k) {
            int i = lane * 4 + k;
            if (i < NB) { bbase[i] = run; bcur[i] = run; run += v[k]; }
        }
        if (lane == 63) bbase[NB] = run;   // == NE
    }
}

// Pass 3: block-aggregated append into bucket regions.
// payload: {src, (dstLocal<<23) | wq23}
__global__ __launch_bounds__(256) void bucket_append(const int* __restrict__ src,
                                                     const int* __restrict__ dst,
                                                     const float* __restrict__ w,
                                                     uint* __restrict__ bcur,
                                                     int2* __restrict__ etmp) {
    __shared__ uint h[NB];
    __shared__ uint res[NB];
    int tid = threadIdx.x;
    if (tid < NB) h[tid] = 0u;
    __syncthreads();
    int e0 = blockIdx.x * 4096 + tid;
    uint rank[16], bkt[16];
#pragma unroll
    for (int k = 0; k < 16; ++k) {
        int e = e0 + 256 * k;
        if (e < NE) {
            uint b = (uint)dst[e] / BSZ;
            bkt[k] = b;
            rank[k] = atomicAdd(&h[b], 1u);
        } else bkt[k] = 0xffffffffu;
    }
    __syncthreads();
    if (tid < NB) res[tid] = h[tid] ? atomicAdd(&bcur[tid], h[tid]) : 0u;
    __syncthreads();
#pragma unroll
    for (int k = 0; k < 16; ++k) {
        if (bkt[k] != 0xffffffffu) {
            int e = e0 + 256 * k;
            uint dl = (uint)dst[e] - bkt[k] * BSZ;
            uint wq = (uint)(w[e] * 8388608.0f);
            if (wq > 8388607u) wq = 8388607u;
            etmp[res[bkt[k]] + rank[k]] = make_int2(src[e], (int)((dl << 23) | wq));
        }
    }
}

// Pass 4: per-bucket (block-exclusive): deg -> dis, per-node scan -> rowstart,
// exact placement with norm' = w * dis[dst]. {cnt,wsum} packed in one u64 LDS slot.
__global__ __launch_bounds__(256) void bucket_build(const int2* __restrict__ etmp,
                                                    const uint* __restrict__ bbase,
                                                    float* __restrict__ dis,
                                                    int* __restrict__ hist_g,
                                                    int* __restrict__ rowstart,
                                                    int2* __restrict__ edges) {
    __shared__ u64   wc[BSZ];       // (count<<40) | sum(wq23)
    __shared__ uint  cur[BSZ];
    __shared__ float disl[BSZ];
    int tid = threadIdx.x;
    int b = blockIdx.x;
    int n0 = b * BSZ;
    for (int i = tid; i < BSZ; i += 256) wc[i] = 0ull;
    __syncthreads();
    uint base = bbase[b], end = bbase[b + 1];
    for (uint i = base + tid; i < end; i += 256) {
        uint y = (uint)etmp[i].y;
        uint dl = y >> 23;
        atomicAdd(&wc[dl], ((u64)1 << 40) | (u64)(y & 0x7fffffu));
    }
    __syncthreads();
    // exclusive scan of counts in wave 0 (chunk of 7 per lane; 7*64=448>=400)
    if (tid < 64) {
        uint v[7], s = 0;
#pragma unroll
        for (int k = 0; k < 7; ++k) {
            int i = tid * 7 + k;
            v[k] = (i < BSZ) ? (uint)(wc[i] >> 40) : 0u;
            s += v[k];
        }
        uint inc = s;
#pragma unroll
        for (int d = 1; d < 64; d <<= 1) {
            uint t = __shfl_up(inc, (unsigned)d, 64);
            if (tid >= d) inc += t;
        }
        uint run = inc - s;
#pragma unroll
        for (int k = 0; k < 7; ++k) {
            int i = tid * 7 + k;
            if (i < BSZ) { cur[i] = run; run += v[k]; }
        }
    }
    __syncthreads();
    // per-node outputs (rowstart snapshot BEFORE placement mutates cur)
    for (int i = tid; i < BSZ; i += 256) {
        u64 v = wc[i];
        float wsum = (float)(v & 0xffffffffffull) * (1.0f / 8388608.0f);
        float ds = rsqrtf(1.0f + wsum);
        disl[i] = ds;
        dis[n0 + i] = ds;
        hist_g[n0 + i] = (int)(v >> 40);
        rowstart[n0 + i] = (int)(base + cur[i]);
    }
    __syncthreads();
    // placement into block-exclusive region [base, end)
    for (uint i = base + tid; i < end; i += 256) {
        int2 e = etmp[i];
        uint y = (uint)e.y;
        uint dl = y >> 23;
        float wv = (float)(y & 0x7fffffu) * (1.0f / 8388608.0f);
        uint p = atomicAdd(&cur[dl], 1u);
        float nrm = wv * disl[dl];
        edges[base + p] = make_int2(e.x, __float_as_int(nrm));
    }
}

// ---------------- MFMA GEMM: HB[r,:] = bf16( (X[r,:] @ W) * dis[r] ) ----------------
// Grid-stride over 64-row tiles; W staged once per block (2 tiles/block typical).
// W transposed in LDS (Wt[n][k], bf16, stride 136 -> 16B-aligned ds_read_b128,
// <=2-way bank aliasing = free). Layouts (m89/m91): A: m=lane&15, k=(lane>>4)*8+j;
// B: n=lane&15, same k; D: col=lane&15, row=(lane>>4)*4+reg.
#define WTS 136
#define NTILES ((NN + 63) / 64)

template <bool AF32>
__global__ __launch_bounds__(256) void gemm_mfma(const void* __restrict__ Xv,
                                                 const float* __restrict__ W,
                                                 const float* __restrict__ dis,
                                                 ushort* __restrict__ HB) {
    __shared__ ushort Wt[DD * WTS];        // 34 KB
    int tid = threadIdx.x;
#pragma unroll
    for (int it = 0; it < 16; ++it) {
        int flat = (tid + it * 256) * 4;   // k*128 + n
        int k = flat >> 7, n = flat & 127;
        float4 wv = *(const float4*)&W[flat];
        Wt[(n + 0) * WTS + k] = (ushort)f2bf(wv.x);
        Wt[(n + 1) * WTS + k] = (ushort)f2bf(wv.y);
        Wt[(n + 2) * WTS + k] = (ushort)f2bf(wv.z);
        Wt[(n + 3) * WTS + k] = (ushort)f2bf(wv.w);
    }
    __syncthreads();

    int wave = tid >> 6, lane = tid & 63;
    int q = lane >> 4, l16 = lane & 15;

    for (int tile = blockIdx.x; tile < NTILES; tile += gridDim.x) {
        int row0 = tile * 64 + wave * 16;

        int arow = row0 + l16;
        if (arow >= NN) arow = NN - 1;
        short8 afr[4];
        if (AF32) {
            const float* xr = (const float*)Xv + (size_t)arow * DD + q * 8;
#pragma unroll
            for (int ks = 0; ks < 4; ++ks) {
                float4 f0 = *(const float4*)(xr + ks * 32);
                float4 f1 = *(const float4*)(xr + ks * 32 + 4);
                uint4 u;
                u.x = f2bf(f0.x) | (f2bf(f0.y) << 16);
                u.y = f2bf(f0.z) | (f2bf(f0.w) << 16);
                u.z = f2bf(f1.x) | (f2bf(f1.y) << 16);
                u.w = f2bf(f1.z) | (f2bf(f1.w) << 16);
                afr[ks] = __builtin_bit_cast(short8, u);
            }
        } else {
            const ushort* xr = (const ushort*)Xv + (size_t)arow * DD + q * 8;
#pragma unroll
            for (int ks = 0; ks < 4; ++ks)
                afr[ks] = *(const short8*)(xr + ks * 32);
        }

        floatx4 acc[8];
#pragma unroll
        for (int ct = 0; ct < 8; ++ct) acc[ct] = (floatx4)(0.0f);

#pragma unroll
        for (int ct = 0; ct < 8; ++ct) {
            const ushort* wp = &Wt[(ct * 16 + l16) * WTS + q * 8];
#pragma unroll
            for (int ks = 0; ks < 4; ++ks) {
                short8 bfr = *(const short8*)(wp + ks * 32);
                acc[ct] = __builtin_amdgcn_mfma_f32_16x16x32_bf16(afr[ks], bfr, acc[ct], 0, 0, 0);
            }
        }

#pragma unroll
        for (int reg = 0; reg < 4; ++reg) {
            int r = row0 + q * 4 + reg;
            if (r < NN) {
                float ds = dis[r];
                ushort* orow = HB + (size_t)r * DD + l16;
#pragma unroll
                for (int ct = 0; ct < 8; ++ct)
                    orow[ct * 16] = (ushort)f2bf(acc[ct][reg] * ds);
            }
        }
    }
}

// decode 4 bf16 (uint2) -> float4
__device__ inline float4 bf4(uint2 u) {
    float4 f;
    f.x = __uint_as_float(u.x << 16);
    f.y = __uint_as_float(u.x & 0xffff0000u);
    f.z = __uint_as_float(u.y << 16);
    f.w = __uint_as_float(u.y & 0xffff0000u);
    return f;
}

// ---------------- fused gather + self-loop + bias + PReLU ----------------
// lane = 4 channels; 32 lanes/node; 8 nodes per 256-block; 8-edge unroll.
// BF16OUT: layer-1 writes bf16 x1 (halves write + next GEMM's read traffic).
template <bool BF16OUT>
__global__ __launch_bounds__(256) void gather_finalize(const ushort* __restrict__ hb,
                                                       const int2* __restrict__ edges,
                                                       const int* __restrict__ rowstart,
                                                       const int* __restrict__ hist,
                                                       const float* __restrict__ dis,
                                                       const float* __restrict__ b,
                                                       const float* __restrict__ a,
                                                       void* __restrict__ xout) {
    int tid = threadIdx.x;
    int lane = tid & 31;                      // channels lane*4 .. lane*4+3
    int node = blockIdx.x * 8 + (tid >> 5);   // NN % 8 == 0

    const int2* ep = edges + rowstart[node];
    int cnt = hist[node];
    float ds = dis[node];

    const uint2* hrow = (const uint2*)(hb + (size_t)node * DD) + lane;
    float4 self = bf4(*hrow);
    float4 acc0, acc1, acc2, acc3;
    acc0.x = self.x * ds; acc0.y = self.y * ds;
    acc0.z = self.z * ds; acc0.w = self.w * ds;
    acc1 = make_float4(0.f, 0.f, 0.f, 0.f);
    acc2 = make_float4(0.f, 0.f, 0.f, 0.f);
    acc3 = make_float4(0.f, 0.f, 0.f, 0.f);

    int j = 0;
    for (; j + 8 <= cnt; j += 8) {
        int2 e0 = ep[j];     int2 e1 = ep[j + 1];
        int2 e2 = ep[j + 2]; int2 e3 = ep[j + 3];
        int2 e4 = ep[j + 4]; int2 e5 = ep[j + 5];
        int2 e6 = ep[j + 6]; int2 e7 = ep[j + 7];
        uint2 u0 = *((const uint2*)(hb + (size_t)e0.x * DD) + lane);
        uint2 u1 = *((const uint2*)(hb + (size_t)e1.x * DD) + lane);
        uint2 u2 = *((const uint2*)(hb + (size_t)e2.x * DD) + lane);
        uint2 u3 = *((const uint2*)(hb + (size_t)e3.x * DD) + lane);
        uint2 u4 = *((const uint2*)(hb + (size_t)e4.x * DD) + lane);
        uint2 u5 = *((const uint2*)(hb + (size_t)e5.x * DD) + lane);
        uint2 u6 = *((const uint2*)(hb + (size_t)e6.x * DD) + lane);
        uint2 u7 = *((const uint2*)(hb + (size_t)e7.x * DD) + lane);
        float n0 = __int_as_float(e0.y), n1 = __int_as_float(e1.y);
        float n2 = __int_as_float(e2.y), n3 = __int_as_float(e3.y);
        float n4 = __int_as_float(e4.y), n5 = __int_as_float(e5.y);
        float n6 = __int_as_float(e6.y), n7 = __int_as_float(e7.y);
        float4 v0 = bf4(u0), v1 = bf4(u1), v2 = bf4(u2), v3 = bf4(u3);
        float4 v4 = bf4(u4), v5 = bf4(u5), v6 = bf4(u6), v7 = bf4(u7);
        acc0.x += v0.x * n0; acc0.y += v0.y * n0; acc0.z += v0.z * n0; acc0.w += v0.w * n0;
        acc1.x += v1.x * n1; acc1.y += v1.y * n1; acc1.z += v1.z * n1; acc1.w += v1.w * n1;
        acc2.x += v2.x * n2; acc2.y += v2.y * n2; acc2.z += v2.z * n2; acc2.w += v2.w * n2;
        acc3.x += v3.x * n3; acc3.y += v3.y * n3; acc3.z += v3.z * n3; acc3.w += v3.w * n3;
        acc0.x += v4.x * n4; acc0.y += v4.y * n4; acc0.z += v4.z * n4; acc0.w += v4.w * n4;
        acc1.x += v5.x * n5; acc1.y += v5.y * n5; acc1.z += v5.z * n5; acc1.w += v5.w * n5;
        acc2.x += v6.x * n6; acc2.y += v6.y * n6; acc2.z += v6.z * n6; acc2.w += v6.w * n6;
        acc3.x += v7.x * n7; acc3.y += v7.y * n7; acc3.z += v7.z * n7; acc3.w += v7.w * n7;
    }
    for (; j < cnt; ++j) {
        int2 e = ep[j];
        uint2 u = *((const uint2*)(hb + (size_t)e.x * DD) + lane);
        float n = __int_as_float(e.y);
        float4 v = bf4(u);
        acc0.x += v.x * n; acc0.y += v.y * n; acc0.z += v.z * n; acc0.w += v.w * n;
    }

    float4 bb = ((const float4*)b)[lane];
    float4 aa = ((const float4*)a)[lane];
    float4 r;
    r.x = acc0.x + acc1.x + acc2.x + acc3.x + bb.x;
    r.y = acc0.y + acc1.y + acc2.y + acc3.y + bb.y;
    r.z = acc0.z + acc1.z + acc2.z + acc3.z + bb.z;
    r.w = acc0.w + acc1.w + acc2.w + acc3.w + bb.w;
    r.x = r.x >= 0.f ? r.x : aa.x * r.x;
    r.y = r.y >= 0.f ? r.y : aa.y * r.y;
    r.z = r.z >= 0.f ? r.z : aa.z * r.z;
    r.w = r.w >= 0.f ? r.w : aa.w * r.w;
    if (BF16OUT) {
        uint2 o;
        o.x = f2bf(r.x) | (f2bf(r.y) << 16);
        o.y = f2bf(r.z) | (f2bf(r.w) << 16);
        ((uint2*)xout)[(size_t)node * 32 + lane] = o;
    } else {
        ((float4*)xout)[(size_t)node * 32 + lane] = r;
    }
}

extern "C" void kernel_launch(void* const* d_in, const int* in_sizes, int n_in,
                              void* d_out, int out_size, void* d_ws, size_t ws_size,
                              hipStream_t stream) {
    const float* feat = (const float*)d_in[0];
    const int*   ei   = (const int*)d_in[1];     // [2, NE]
    const float* ew   = (const float*)d_in[2];
    const float* W1   = (const float*)d_in[3];
    const float* b1   = (const float*)d_in[4];
    const float* a1   = (const float*)d_in[5];
    const float* W2   = (const float*)d_in[6];
    const float* b2   = (const float*)d_in[7];
    const float* a2   = (const float*)d_in[8];
    float* out = (float*)d_out;

    const int* srcp = ei;
    const int* dstp = ei + NE;

    // workspace carve (bytes) — ~58 MB
    char* wsb = (char*)d_ws;
    size_t off = 0;
    uint* bc     = (uint*)(wsb + off); off += 4096;                 // NB counts
    uint* bbase  = (uint*)(wsb + off); off += 4096;                 // NB+1
    uint* bcur   = (uint*)(wsb + off); off += 4096;                 // NB
    float* dis   = (float*)(wsb + off); off += 4ull * NN;           // NN
    int* hist    = (int*)(wsb + off); off += 4ull * NN;             // NN
    int* rowstart= (int*)(wsb + off); off += 4ull * NN;             // NN
    int2* etmp   = (int2*)(wsb + off); off += 8ull * NE;            // NE
    int2* edges  = (int2*)(wsb + off); off += 8ull * NE;            // NE
    ushort* hb   = (ushort*)(wsb + off); off += 2ull * NN * DD;     // NN*DD bf16
    ushort* x1b  = (ushort*)(wsb + off); off += 2ull * NN * DD;     // NN*DD bf16

    // ---- CSR build (bucketed counting sort) ----
    zero_bc<<<1, 256, 0, stream>>>(bc);
    bucket_hist<<<(NE + 8191) / 8192, 256, 0, stream>>>(dstp, bc);
    bucket_prefix<<<1, 256, 0, stream>>>(bc, bbase, bcur);
    bucket_append<<<(NE + 4095) / 4096, 256, 0, stream>>>(srcp, dstp, ew, bcur, etmp);
    bucket_build<<<NB, 256, 0, stream>>>(etmp, bbase, dis, hist, rowstart, edges);

    const int gemm_blocks = (NTILES + 1) / 2;   // 2 tiles/block
    const int gath_blocks = NN / 8;

    // ---- layer 1 ----
    gemm_mfma<true><<<gemm_blocks, 256, 0, stream>>>(feat, W1, dis, hb);
    gather_finalize<true><<<gath_blocks, 256, 0, stream>>>(hb, edges, rowstart, hist, dis, b1, a1, x1b);
    // ---- layer 2 ----
    gemm_mfma<false><<<gemm_blocks, 256, 0, stream>>>(x1b, W2, dis, hb);
    gather_finalize<false><<<gath_blocks, 256, 0, stream>>>(hb, edges, rowstart, hist, dis, b2, a2, out);
}